// Round 9
// baseline (76.204 us; speedup 1.0000x reference)
//
#include <hip/hip_runtime.h>

constexpr int BSZ = 512;
constexpr int DIM = 128;
constexpr int NREG = 6;                 // 6*64 = 384 register-cached negative slots
#define MARGIN_F 0.2f
#define EPS_F 1e-6f

// Workspace layout:
//   [0, 1MB)          : D matrix (512*512 f32)
//   [1MB, +4KB)       : num_part (512 f64)
//   [1MB+4KB, +2KB)   : den_part (512 i32)
//   [1MB+8KB)         : done counter (own cacheline; memset to 0 each call)

// Kernel A: materialize D[i,j] = ||f_i - f_j + eps||_2 once, 32x32 tiles.
// Coalesced: 256 blocks x 32 KB = 8 MB logical reads (vs 131 MB uncoalesced
// fused version, which the concurrent 262 MB poison blit turned into 71 MB
// of contended HBM fetch).
__global__ __launch_bounds__(256) void dist_tile(
    const float* __restrict__ feat, float* __restrict__ D) {
  const int bi = blockIdx.x >> 4;       // 1-D grid: 256 blocks -> 16x16 tiles
  const int bj = blockIdx.x & 15;
  const int tid = threadIdx.x;

  __shared__ float4 At[32][33];         // pitch 33 breaks bank aliasing
  __shared__ float4 Bt[32][33];

  const float4* ga = (const float4*)feat + (size_t)bi * 32 * (DIM / 4);
  const float4* gb = (const float4*)feat + (size_t)bj * 32 * (DIM / 4);
#pragma unroll
  for (int k = 0; k < 4; ++k) {
    const int idx = tid + k * 256;      // 0..1023, coalesced
    const int row = idx >> 5;
    const int col = idx & 31;
    float4 va = ga[idx];
    va.x += EPS_F; va.y += EPS_F; va.z += EPS_F; va.w += EPS_F;
    At[row][col] = va;                  // EPS folded: (a+eps)-b == a-b+eps
    Bt[row][col] = gb[idx];
  }
  __syncthreads();

  const int r0 = tid >> 4;
  const int c0 = tid & 15;
  float s00 = 0.f, s01 = 0.f, s10 = 0.f, s11 = 0.f;
#pragma unroll
  for (int d = 0; d < DIM / 4; ++d) {
    const float4 a0 = At[r0][d];
    const float4 a1 = At[r0 + 16][d];
    const float4 b0 = Bt[c0][d];
    const float4 b1 = Bt[c0 + 16][d];
    float x;
    x = a0.x - b0.x; s00 = fmaf(x, x, s00);
    x = a0.y - b0.y; s00 = fmaf(x, x, s00);
    x = a0.z - b0.z; s00 = fmaf(x, x, s00);
    x = a0.w - b0.w; s00 = fmaf(x, x, s00);
    x = a0.x - b1.x; s01 = fmaf(x, x, s01);
    x = a0.y - b1.y; s01 = fmaf(x, x, s01);
    x = a0.z - b1.z; s01 = fmaf(x, x, s01);
    x = a0.w - b1.w; s01 = fmaf(x, x, s01);
    x = a1.x - b0.x; s10 = fmaf(x, x, s10);
    x = a1.y - b0.y; s10 = fmaf(x, x, s10);
    x = a1.z - b0.z; s10 = fmaf(x, x, s10);
    x = a1.w - b0.w; s10 = fmaf(x, x, s10);
    x = a1.x - b1.x; s11 = fmaf(x, x, s11);
    x = a1.y - b1.y; s11 = fmaf(x, x, s11);
    x = a1.z - b1.z; s11 = fmaf(x, x, s11);
    x = a1.w - b1.w; s11 = fmaf(x, x, s11);
  }
  float* Drow0 = D + (size_t)(bi * 32 + r0) * BSZ + bj * 32;
  float* Drow1 = D + (size_t)(bi * 32 + r0 + 16) * BSZ + bj * 32;
  Drow0[c0]      = sqrtf(s00);
  Drow0[c0 + 16] = sqrtf(s01);
  Drow1[c0]      = sqrtf(s10);
  Drow1[c0 + 16] = sqrtf(s11);
}

// Kernel B: one block (512 thr) per anchor; fused finalize via last-block.
// Partials = plain stores to distinct addresses (rounds 4->5 A/B: same-line
// atomics from all blocks cost ~12 us). ONE atomic per block (done counter,
// own cacheline). Last block atomic-reads partials (device-coherent).
__global__ __launch_bounds__(512, 4) void triplet_fused(
    const float* __restrict__ D, const int* __restrict__ mask,
    double* __restrict__ num_part, int* __restrict__ den_part,
    unsigned int* __restrict__ done, float* __restrict__ out) {
  const int i = blockIdx.x;
  const int tid = threadIdx.x;
  const int wave = tid >> 6;
  const int lane = tid & 63;

  __shared__ float apos[BSZ];
  __shared__ float bneg[BSZ];
  __shared__ int wtot[8][2];
  __shared__ float wred[8];
  __shared__ int slast;

  const float dist = D[(size_t)i * BSZ + tid];     // coalesced dword
  const int m = mask[(size_t)i * BSZ + tid];
  const bool is_pos = (m != 0);
  const bool is_neg = (m == 0) && (tid != i);

  const unsigned long long bp = __ballot(is_pos);
  const unsigned long long bn = __ballot(is_neg);
  const unsigned long long ltm = (1ull << lane) - 1ull;
  const int p_before = __popcll(bp & ltm);
  const int n_before = __popcll(bn & ltm);
  if (lane == 0) { wtot[wave][0] = __popcll(bp); wtot[wave][1] = __popcll(bn); }
  __syncthreads();

  int pbase = 0, nbase = 0, nP = 0, nN = 0;
#pragma unroll
  for (int w = 0; w < 8; ++w) {
    const int tp = wtot[w][0], tn = wtot[w][1];
    if (w < wave) { pbase += tp; nbase += tn; }
    nP += tp; nN += tn;
  }
  if (is_pos)      apos[pbase + p_before] = dist + MARGIN_F;
  else if (is_neg) bneg[nbase + n_before] = dist;

  const int nPpad = (nP + 31) & ~31;
  { const int j = nP + tid; if (j < nPpad) apos[j] = -1e30f; }    // relu -> 0
  { const int k = nN + tid; if (k < NREG * 64) bneg[k] = 1e30f; } // relu -> 0
  __syncthreads();

  float bnr[NREG];
#pragma unroll
  for (int r = 0; r < NREG; ++r) bnr[r] = bneg[lane + 64 * r];

  float acc[NREG];
#pragma unroll
  for (int r = 0; r < NREG; ++r) acc[r] = 0.f;

  const float4* apos4 = (const float4*)apos;
  const int nj4 = nPpad >> 2;
  for (int j4 = wave; j4 < nj4; j4 += 8) {
    const float4 a = apos4[j4];                    // uniform addr: LDS broadcast
#pragma unroll
    for (int r = 0; r < NREG; ++r) {
      acc[r] += fmaxf(a.x - bnr[r], 0.f);
      acc[r] += fmaxf(a.y - bnr[r], 0.f);
      acc[r] += fmaxf(a.z - bnr[r], 0.f);
      acc[r] += fmaxf(a.w - bnr[r], 0.f);
    }
  }
  float lsum = 0.f;
#pragma unroll
  for (int r = 0; r < NREG; ++r) lsum += acc[r];

  if (nN > NREG * 64) {                            // rare statistical tail
    for (int j = wave; j < nP; j += 8) {
      const float aj = apos[j];
      for (int k = NREG * 64 + lane; k < nN; k += 64)
        lsum += fmaxf(aj - bneg[k], 0.f);
    }
  }

  for (int off = 32; off > 0; off >>= 1) lsum += __shfl_down(lsum, off, 64);
  if (lane == 0) wred[wave] = lsum;
  __syncthreads();
  if (tid == 0) {
    float bsum = 0.f;
#pragma unroll
    for (int w = 0; w < 8; ++w) bsum += wred[w];
    num_part[i] = (double)bsum;                    // plain store, distinct addr
    den_part[i] = nP * nN;
    __threadfence();                               // release partials
    slast = (atomicAdd(done, 1u) == (unsigned)(BSZ - 1));
  }
  __syncthreads();

  if (slast) {                                     // last block: finalize
    __threadfence();                               // acquire
    double n = atomicAdd(&num_part[tid], 0.0);     // device-coherent read
    long long d = (long long)atomicAdd(&den_part[tid], 0);
    __shared__ double sn[8];
    __shared__ long long sd[8];
    for (int off = 32; off > 0; off >>= 1) {
      n += __shfl_down(n, off, 64);
      d += __shfl_down(d, off, 64);
    }
    if (lane == 0) { sn[wave] = n; sd[wave] = d; }
    __syncthreads();
    if (tid == 0) {
      double N = 0.0; long long Dn = 0;
#pragma unroll
      for (int w = 0; w < 8; ++w) { N += sn[w]; Dn += sd[w]; }
      out[0] = (Dn > 0) ? (float)(N / (double)Dn) : 0.0f;
    }
  }
}

extern "C" void kernel_launch(void* const* d_in, const int* in_sizes, int n_in,
                              void* d_out, int out_size, void* d_ws, size_t ws_size,
                              hipStream_t stream) {
  const float* feat = (const float*)d_in[0];
  const int* mask = (const int*)d_in[1];
  float* out = (float*)d_out;

  char* ws = (char*)d_ws;
  float* Dm = (float*)ws;                                    // 1 MB
  double* num_part = (double*)(ws + (1 << 20));              // 4 KB
  int* den_part = (int*)(ws + (1 << 20) + 4096);             // 2 KB
  unsigned int* done = (unsigned int*)(ws + (1 << 20) + 8192); // own line

  hipMemsetAsync(done, 0, sizeof(unsigned int), stream);     // ws is re-poisoned
  dist_tile<<<256, 256, 0, stream>>>(feat, Dm);
  triplet_fused<<<BSZ, 512, 0, stream>>>(Dm, mask, num_part, den_part, done, out);
}

// Round 11
// 75.075 us; speedup vs baseline: 1.0150x; 1.0150x over previous
//
#include <hip/hip_runtime.h>

constexpr int BSZ = 512;
constexpr int DIM = 128;
constexpr int NREG = 6;                 // 6*64 = 384 register-cached negative slots
#define MARGIN_F 0.2f
#define EPS_F 1e-6f

// Workspace layout:
//   [0, 1MB)          : D matrix (512*512 f32)
//   [1MB, +4KB)       : num_part (512 f64)
//   [1MB+4KB, +2KB)   : den_part (512 i32)
//   [1MB+8KB)         : done counter (own cacheline; NEVER zeroed — the
//                       last-block test is wrap-agnostic: (old & 511) == 511.
//                       512 increments/call cover 512 consecutive values, so
//                       exactly one block fires regardless of start value.)

// Kernel A: materialize D[i,j] = ||f_i - f_j + eps||_2 once, 32x32 tiles.
// Coalesced: 256 blocks x 32 KB = 8 MB logical reads (vs 131 MB uncoalesced
// fused version, which the concurrent 262 MB poison blit turned into 71 MB
// of contended HBM fetch).
__global__ __launch_bounds__(256) void dist_tile(
    const float* __restrict__ feat, float* __restrict__ D) {
  const int bi = blockIdx.x >> 4;       // 1-D grid: 256 blocks -> 16x16 tiles
  const int bj = blockIdx.x & 15;
  const int tid = threadIdx.x;

  __shared__ float4 At[32][33];         // pitch 33 breaks bank aliasing
  __shared__ float4 Bt[32][33];

  const float4* ga = (const float4*)feat + (size_t)bi * 32 * (DIM / 4);
  const float4* gb = (const float4*)feat + (size_t)bj * 32 * (DIM / 4);
#pragma unroll
  for (int k = 0; k < 4; ++k) {
    const int idx = tid + k * 256;      // 0..1023, coalesced
    const int row = idx >> 5;
    const int col = idx & 31;
    float4 va = ga[idx];
    va.x += EPS_F; va.y += EPS_F; va.z += EPS_F; va.w += EPS_F;
    At[row][col] = va;                  // EPS folded: (a+eps)-b == a-b+eps
    Bt[row][col] = gb[idx];
  }
  __syncthreads();

  const int r0 = tid >> 4;
  const int c0 = tid & 15;
  float s00 = 0.f, s01 = 0.f, s10 = 0.f, s11 = 0.f;
#pragma unroll
  for (int d = 0; d < DIM / 4; ++d) {
    const float4 a0 = At[r0][d];
    const float4 a1 = At[r0 + 16][d];
    const float4 b0 = Bt[c0][d];
    const float4 b1 = Bt[c0 + 16][d];
    float x;
    x = a0.x - b0.x; s00 = fmaf(x, x, s00);
    x = a0.y - b0.y; s00 = fmaf(x, x, s00);
    x = a0.z - b0.z; s00 = fmaf(x, x, s00);
    x = a0.w - b0.w; s00 = fmaf(x, x, s00);
    x = a0.x - b1.x; s01 = fmaf(x, x, s01);
    x = a0.y - b1.y; s01 = fmaf(x, x, s01);
    x = a0.z - b1.z; s01 = fmaf(x, x, s01);
    x = a0.w - b1.w; s01 = fmaf(x, x, s01);
    x = a1.x - b0.x; s10 = fmaf(x, x, s10);
    x = a1.y - b0.y; s10 = fmaf(x, x, s10);
    x = a1.z - b0.z; s10 = fmaf(x, x, s10);
    x = a1.w - b0.w; s10 = fmaf(x, x, s10);
    x = a1.x - b1.x; s11 = fmaf(x, x, s11);
    x = a1.y - b1.y; s11 = fmaf(x, x, s11);
    x = a1.z - b1.z; s11 = fmaf(x, x, s11);
    x = a1.w - b1.w; s11 = fmaf(x, x, s11);
  }
  float* Drow0 = D + (size_t)(bi * 32 + r0) * BSZ + bj * 32;
  float* Drow1 = D + (size_t)(bi * 32 + r0 + 16) * BSZ + bj * 32;
  Drow0[c0]      = sqrtf(s00);
  Drow0[c0 + 16] = sqrtf(s01);
  Drow1[c0]      = sqrtf(s10);
  Drow1[c0 + 16] = sqrtf(s11);
}

// Kernel B: one block (512 thr) per anchor; fused finalize via last-block.
// Partials = plain stores to distinct addresses (rounds 4->5 A/B: same-line
// atomics from all blocks cost ~12 us). ONE atomic per block (done counter
// on its own line, wrap-agnostic test). Last block atomic-reads partials.
__global__ __launch_bounds__(512, 4) void triplet_fused(
    const float* __restrict__ D, const int* __restrict__ mask,
    double* __restrict__ num_part, int* __restrict__ den_part,
    unsigned int* __restrict__ done, float* __restrict__ out) {
  const int i = blockIdx.x;
  const int tid = threadIdx.x;
  const int wave = tid >> 6;
  const int lane = tid & 63;

  __shared__ float apos[BSZ];
  __shared__ float bneg[BSZ];
  __shared__ int wtot[8][2];
  __shared__ float wred[8];
  __shared__ int slast;

  const float dist = D[(size_t)i * BSZ + tid];     // coalesced dword
  const int m = mask[(size_t)i * BSZ + tid];
  const bool is_pos = (m != 0);
  const bool is_neg = (m == 0) && (tid != i);

  const unsigned long long bp = __ballot(is_pos);
  const unsigned long long bn = __ballot(is_neg);
  const unsigned long long ltm = (1ull << lane) - 1ull;
  const int p_before = __popcll(bp & ltm);
  const int n_before = __popcll(bn & ltm);
  if (lane == 0) { wtot[wave][0] = __popcll(bp); wtot[wave][1] = __popcll(bn); }
  __syncthreads();

  int pbase = 0, nbase = 0, nP = 0, nN = 0;
#pragma unroll
  for (int w = 0; w < 8; ++w) {
    const int tp = wtot[w][0], tn = wtot[w][1];
    if (w < wave) { pbase += tp; nbase += tn; }
    nP += tp; nN += tn;
  }
  if (is_pos)      apos[pbase + p_before] = dist + MARGIN_F;
  else if (is_neg) bneg[nbase + n_before] = dist;

  const int nPpad = (nP + 31) & ~31;
  { const int j = nP + tid; if (j < nPpad) apos[j] = -1e30f; }    // relu -> 0
  { const int k = nN + tid; if (k < NREG * 64) bneg[k] = 1e30f; } // relu -> 0
  __syncthreads();

  float bnr[NREG];
#pragma unroll
  for (int r = 0; r < NREG; ++r) bnr[r] = bneg[lane + 64 * r];

  float acc[NREG];
#pragma unroll
  for (int r = 0; r < NREG; ++r) acc[r] = 0.f;

  const float4* apos4 = (const float4*)apos;
  const int nj4 = nPpad >> 2;
  for (int j4 = wave; j4 < nj4; j4 += 8) {
    const float4 a = apos4[j4];                    // uniform addr: LDS broadcast
#pragma unroll
    for (int r = 0; r < NREG; ++r) {
      acc[r] += fmaxf(a.x - bnr[r], 0.f);
      acc[r] += fmaxf(a.y - bnr[r], 0.f);
      acc[r] += fmaxf(a.z - bnr[r], 0.f);
      acc[r] += fmaxf(a.w - bnr[r], 0.f);
    }
  }
  float lsum = 0.f;
#pragma unroll
  for (int r = 0; r < NREG; ++r) lsum += acc[r];

  if (nN > NREG * 64) {                            // rare statistical tail
    for (int j = wave; j < nP; j += 8) {
      const float aj = apos[j];
      for (int k = NREG * 64 + lane; k < nN; k += 64)
        lsum += fmaxf(aj - bneg[k], 0.f);
    }
  }

  for (int off = 32; off > 0; off >>= 1) lsum += __shfl_down(lsum, off, 64);
  if (lane == 0) wred[wave] = lsum;
  __syncthreads();
  if (tid == 0) {
    float bsum = 0.f;
#pragma unroll
    for (int w = 0; w < 8; ++w) bsum += wred[w];
    num_part[i] = (double)bsum;                    // plain store, distinct addr
    den_part[i] = nP * nN;
    __threadfence();                               // release partials
    const unsigned int old = atomicAdd(done, 1u);
    slast = ((old & (unsigned)(BSZ - 1)) == (unsigned)(BSZ - 1));
  }
  __syncthreads();

  if (slast) {                                     // last block: finalize
    __threadfence();                               // acquire
    double n = atomicAdd(&num_part[tid], 0.0);     // device-coherent read
    long long d = (long long)atomicAdd(&den_part[tid], 0);
    __shared__ double sn[8];
    __shared__ long long sd[8];
    for (int off = 32; off > 0; off >>= 1) {
      n += __shfl_down(n, off, 64);
      d += __shfl_down(d, off, 64);
    }
    if (lane == 0) { sn[wave] = n; sd[wave] = d; }
    __syncthreads();
    if (tid == 0) {
      double N = 0.0; long long Dn = 0;
#pragma unroll
      for (int w = 0; w < 8; ++w) { N += sn[w]; Dn += sd[w]; }
      out[0] = (Dn > 0) ? (float)(N / (double)Dn) : 0.0f;
    }
  }
}

extern "C" void kernel_launch(void* const* d_in, const int* in_sizes, int n_in,
                              void* d_out, int out_size, void* d_ws, size_t ws_size,
                              hipStream_t stream) {
  const float* feat = (const float*)d_in[0];
  const int* mask = (const int*)d_in[1];
  float* out = (float*)d_out;

  char* ws = (char*)d_ws;
  float* Dm = (float*)ws;                                    // 1 MB
  double* num_part = (double*)(ws + (1 << 20));              // 4 KB
  int* den_part = (int*)(ws + (1 << 20) + 4096);             // 2 KB
  unsigned int* done = (unsigned int*)(ws + (1 << 20) + 8192); // own line

  dist_tile<<<256, 256, 0, stream>>>(feat, Dm);
  triplet_fused<<<BSZ, 512, 0, stream>>>(Dm, mask, num_part, den_part, done, out);
}

// Round 12
// 67.155 us; speedup vs baseline: 1.1347x; 1.1179x over previous
//
#include <hip/hip_runtime.h>

constexpr int BSZ = 512;
constexpr int DIM = 128;
constexpr int NREG = 6;                 // 6*64 = 384 register-cached negative slots
#define MARGIN_F 0.2f
#define EPS_F 1e-6f

// Round-8 structure (best measured: 66.8 us). 3 dispatches, zero atomics.
// Fused last-block finalize (R9/R11) measured consistently ~8-10 us WORSE:
// 512 same-line device atomics serialize at the home L2 and don't overlap
// compute because all blocks finish together (2 blocks/CU).

// Kernel A: materialize D[i,j] = ||f_i - f_j + eps||_2 once, 32x32 tiles.
// Coalesced: 256 blocks x 32 KB = 8 MB logical reads (vs 131 MB uncoalesced
// fused version, which the concurrent 262 MB poison blit turned into 71 MB
// of contended HBM fetch).
__global__ __launch_bounds__(256) void dist_tile(
    const float* __restrict__ feat, float* __restrict__ D) {
  const int bi = blockIdx.x >> 4;       // 1-D grid: 256 blocks -> 16x16 tiles
  const int bj = blockIdx.x & 15;
  const int tid = threadIdx.x;

  __shared__ float4 At[32][33];         // pitch 33 breaks bank aliasing
  __shared__ float4 Bt[32][33];

  const float4* ga = (const float4*)feat + (size_t)bi * 32 * (DIM / 4);
  const float4* gb = (const float4*)feat + (size_t)bj * 32 * (DIM / 4);
#pragma unroll
  for (int k = 0; k < 4; ++k) {
    const int idx = tid + k * 256;      // 0..1023, coalesced
    const int row = idx >> 5;
    const int col = idx & 31;
    float4 va = ga[idx];
    va.x += EPS_F; va.y += EPS_F; va.z += EPS_F; va.w += EPS_F;
    At[row][col] = va;                  // EPS folded: (a+eps)-b == a-b+eps
    Bt[row][col] = gb[idx];
  }
  __syncthreads();

  const int r0 = tid >> 4;
  const int c0 = tid & 15;
  float s00 = 0.f, s01 = 0.f, s10 = 0.f, s11 = 0.f;
#pragma unroll
  for (int d = 0; d < DIM / 4; ++d) {
    const float4 a0 = At[r0][d];
    const float4 a1 = At[r0 + 16][d];
    const float4 b0 = Bt[c0][d];
    const float4 b1 = Bt[c0 + 16][d];
    float x;
    x = a0.x - b0.x; s00 = fmaf(x, x, s00);
    x = a0.y - b0.y; s00 = fmaf(x, x, s00);
    x = a0.z - b0.z; s00 = fmaf(x, x, s00);
    x = a0.w - b0.w; s00 = fmaf(x, x, s00);
    x = a0.x - b1.x; s01 = fmaf(x, x, s01);
    x = a0.y - b1.y; s01 = fmaf(x, x, s01);
    x = a0.z - b1.z; s01 = fmaf(x, x, s01);
    x = a0.w - b1.w; s01 = fmaf(x, x, s01);
    x = a1.x - b0.x; s10 = fmaf(x, x, s10);
    x = a1.y - b0.y; s10 = fmaf(x, x, s10);
    x = a1.z - b0.z; s10 = fmaf(x, x, s10);
    x = a1.w - b0.w; s10 = fmaf(x, x, s10);
    x = a1.x - b1.x; s11 = fmaf(x, x, s11);
    x = a1.y - b1.y; s11 = fmaf(x, x, s11);
    x = a1.z - b1.z; s11 = fmaf(x, x, s11);
    x = a1.w - b1.w; s11 = fmaf(x, x, s11);
  }
  float* Drow0 = D + (size_t)(bi * 32 + r0) * BSZ + bj * 32;
  float* Drow1 = D + (size_t)(bi * 32 + r0 + 16) * BSZ + bj * 32;
  Drow0[c0]      = sqrtf(s00);
  Drow0[c0 + 16] = sqrtf(s01);
  Drow1[c0]      = sqrtf(s10);
  Drow1[c0 + 16] = sqrtf(s11);
}

// Kernel B: one block (512 thr) per anchor. Reads only D-row i (2 KB,
// coalesced) + mask row; ballot-compacts; register-cached negatives vs
// LDS-broadcast positives; uncontended per-block partials (plain stores).
__global__ __launch_bounds__(512, 4) void triplet_main(
    const float* __restrict__ D, const int* __restrict__ mask,
    double* __restrict__ num_part, int* __restrict__ den_part) {
  const int i = blockIdx.x;
  const int tid = threadIdx.x;
  const int wave = tid >> 6;
  const int lane = tid & 63;

  __shared__ float apos[BSZ];       // compacted positives (+margin), pad -1e30
  __shared__ float bneg[BSZ];       // compacted negatives, padded to 384 w/ +1e30
  __shared__ int wtot[8][2];
  __shared__ float wred[8];

  const float dist = D[(size_t)i * BSZ + tid];     // coalesced dword
  const int m = mask[(size_t)i * BSZ + tid];
  const bool is_pos = (m != 0);
  const bool is_neg = (m == 0) && (tid != i);

  const unsigned long long bp = __ballot(is_pos);
  const unsigned long long bn = __ballot(is_neg);
  const unsigned long long ltm = (1ull << lane) - 1ull;
  const int p_before = __popcll(bp & ltm);
  const int n_before = __popcll(bn & ltm);
  if (lane == 0) { wtot[wave][0] = __popcll(bp); wtot[wave][1] = __popcll(bn); }
  __syncthreads();

  int pbase = 0, nbase = 0, nP = 0, nN = 0;
#pragma unroll
  for (int w = 0; w < 8; ++w) {
    const int tp = wtot[w][0], tn = wtot[w][1];
    if (w < wave) { pbase += tp; nbase += tn; }
    nP += tp; nN += tn;
  }
  if (is_pos)      apos[pbase + p_before] = dist + MARGIN_F;
  else if (is_neg) bneg[nbase + n_before] = dist;

  const int nPpad = (nP + 31) & ~31;
  { const int j = nP + tid; if (j < nPpad) apos[j] = -1e30f; }    // relu -> 0
  { const int k = nN + tid; if (k < NREG * 64) bneg[k] = 1e30f; } // relu -> 0
  __syncthreads();

  float bnr[NREG];
#pragma unroll
  for (int r = 0; r < NREG; ++r) bnr[r] = bneg[lane + 64 * r];

  float acc[NREG];
#pragma unroll
  for (int r = 0; r < NREG; ++r) acc[r] = 0.f;

  const float4* apos4 = (const float4*)apos;
  const int nj4 = nPpad >> 2;
  for (int j4 = wave; j4 < nj4; j4 += 8) {
    const float4 a = apos4[j4];                    // uniform addr: LDS broadcast
#pragma unroll
    for (int r = 0; r < NREG; ++r) {
      acc[r] += fmaxf(a.x - bnr[r], 0.f);
      acc[r] += fmaxf(a.y - bnr[r], 0.f);
      acc[r] += fmaxf(a.z - bnr[r], 0.f);
      acc[r] += fmaxf(a.w - bnr[r], 0.f);
    }
  }
  float lsum = 0.f;
#pragma unroll
  for (int r = 0; r < NREG; ++r) lsum += acc[r];

  if (nN > NREG * 64) {                            // rare statistical tail
    for (int j = wave; j < nP; j += 8) {
      const float aj = apos[j];
      for (int k = NREG * 64 + lane; k < nN; k += 64)
        lsum += fmaxf(aj - bneg[k], 0.f);
    }
  }

  for (int off = 32; off > 0; off >>= 1) lsum += __shfl_down(lsum, off, 64);
  if (lane == 0) wred[wave] = lsum;
  __syncthreads();
  if (tid == 0) {
    float bsum = 0.f;
#pragma unroll
    for (int w = 0; w < 8; ++w) bsum += wred[w];
    num_part[i] = (double)bsum;                    // distinct address per block
    den_part[i] = nP * nN;
  }
}

__global__ __launch_bounds__(256) void triplet_finalize(
    const double* __restrict__ num_part, const int* __restrict__ den_part,
    float* __restrict__ out) {
  const int tid = threadIdx.x;
  double n = 0.0;
  long long d = 0;
  for (int i = tid; i < BSZ; i += 256) {
    n += num_part[i];
    d += den_part[i];
  }
  __shared__ double sn[4];
  __shared__ long long sd[4];
  for (int off = 32; off > 0; off >>= 1) {
    n += __shfl_down(n, off, 64);
    d += __shfl_down(d, off, 64);
  }
  if ((tid & 63) == 0) { sn[tid >> 6] = n; sd[tid >> 6] = d; }
  __syncthreads();
  if (tid == 0) {
    const double N = sn[0] + sn[1] + sn[2] + sn[3];
    const long long Dn = sd[0] + sd[1] + sd[2] + sd[3];
    out[0] = (Dn > 0) ? (float)(N / (double)Dn) : 0.0f;
  }
}

extern "C" void kernel_launch(void* const* d_in, const int* in_sizes, int n_in,
                              void* d_out, int out_size, void* d_ws, size_t ws_size,
                              hipStream_t stream) {
  const float* feat = (const float*)d_in[0];
  const int* mask = (const int*)d_in[1];
  float* out = (float*)d_out;

  float* Dm = (float*)d_ws;                                  // 512*512*4 = 1 MB
  double* num_part = (double*)((char*)d_ws + (1 << 20));
  int* den_part = (int*)((char*)d_ws + (1 << 20) + BSZ * sizeof(double));

  dist_tile<<<256, 256, 0, stream>>>(feat, Dm);              // writes all of Dm
  triplet_main<<<BSZ, 512, 0, stream>>>(Dm, mask, num_part, den_part);
  triplet_finalize<<<1, 256, 0, stream>>>(num_part, den_part, out);
}